// Round 9
// baseline (46.275 us; speedup 1.0000x reference)
//
#include <hip/hip_runtime.h>
#include <hip/hip_bf16.h>

// out[b,i,j,o] = (x[b,min]·M_lo[o] + s_lo[o]) + (x[b,max]·M_hi[o] + s_hi[o])
// where M_lo[o] = W1^T Wc[o,:100], M_hi[o] = W1^T Wc[o,100:],
//       s_lo[o] = b1·Wc[o,:100] + bc[o], s_hi[o] = b1·Wc[o,100:].
//
// R9: R8 structure (barrier-free, one wave per batch) with
//   - 512-thread blocks (8 waves): half the block launches / M reloads
//   - 3-deep register prefetch (6 x-loads in flight per wave)

#define NA 13
#define DM 512
#define NOH 8   // 4 outputs x {lo,hi}
#define LEN 100
#define WPB 8   // waves per block

typedef float fv4 __attribute__((ext_vector_type(4)));

__global__ __launch_bounds__(512) void precompute_M(
    const float* __restrict__ W1, const float* __restrict__ b1,
    const float* __restrict__ Wc, const float* __restrict__ bc,
    float* __restrict__ M, float* __restrict__ s) {
    __shared__ float W1s[LEN * 64];
    const int tid = threadIdx.x;
    const int d_base = blockIdx.x * 64;

#pragma unroll
    for (int r = 0; r < 4; ++r) {
        int idx = tid + r * 512;
        if (idx < LEN * 16) {
            int c = idx >> 4, d4 = idx & 15;
            *(fv4*)(W1s + c * 64 + d4 * 4) =
                *(const fv4*)(W1 + c * DM + d_base + d4 * 4);
        }
    }
    __syncthreads();

    const int oh = tid >> 6;      // wave-uniform: 0..7
    const int d = tid & 63;
    const int o = oh & 3, half = oh >> 2;
    const float* wc = Wc + o * 200 + half * 100;   // wave-uniform pointer

    float a0 = 0.f, a1 = 0.f, a2 = 0.f, a3 = 0.f;
#pragma unroll
    for (int c = 0; c < LEN; c += 4) {
        a0 = fmaf(wc[c + 0], W1s[(c + 0) * 64 + d], a0);
        a1 = fmaf(wc[c + 1], W1s[(c + 1) * 64 + d], a1);
        a2 = fmaf(wc[c + 2], W1s[(c + 2) * 64 + d], a2);
        a3 = fmaf(wc[c + 3], W1s[(c + 3) * 64 + d], a3);
    }
    M[oh * DM + d_base + d] = (a0 + a1) + (a2 + a3);

    if (blockIdx.x == 0) {
        float p = wc[d] * b1[d];
        if (d < LEN - 64) p = fmaf(wc[d + 64], b1[d + 64], p);
#pragma unroll
        for (int m = 32; m >= 1; m >>= 1) p += __shfl_xor(p, m, 64);
        if (d == 0) s[oh] = p + ((half == 0) ? bc[o] : 0.f);
    }
}

__global__ __launch_bounds__(512) void edge_main(
    const float* __restrict__ x, const float* __restrict__ M,
    const float* __restrict__ s, float* __restrict__ out) {
    const int lane = threadIdx.x & 63;
    const int wave = threadIdx.x >> 6;
    const int b = blockIdx.x * WPB + wave;        // one batch per wave

    const float* xb = x + (size_t)b * (NA * DM);

    // 3-deep register prefetch over the 13 rows; first loads issued
    // before the M loads so HBM latency hides under them.
    fv4 pA0, pB0, pA1, pB1, pA2, pB2;
    pA0 = *(const fv4*)(xb + lane * 4);
    pB0 = *(const fv4*)(xb + 256 + lane * 4);
    pA1 = *(const fv4*)(xb + DM + lane * 4);
    pB1 = *(const fv4*)(xb + DM + 256 + lane * 4);
    pA2 = *(const fv4*)(xb + 2 * DM + lane * 4);
    pB2 = *(const fv4*)(xb + 2 * DM + 256 + lane * 4);

    // Per-lane M slices: lane covers d = lane*4..+3 and d = 256+lane*4..+3
    fv4 mA[NOH], mB[NOH];
#pragma unroll
    for (int oh = 0; oh < NOH; ++oh) {
        mA[oh] = *(const fv4*)(M + oh * DM + lane * 4);
        mB[oh] = *(const fv4*)(M + oh * DM + 256 + lane * 4);
    }
    const float s_lane = s[lane & 7];

    const bool m1 = (lane & 1) != 0;
    const bool m2 = (lane & 2) != 0;
    const bool m4 = (lane & 4) != 0;

    __shared__ float GW[WPB][NA][NOH];   // private slab per wave

#pragma unroll
    for (int a = 0; a < NA; ++a) {
        const int ph = a % 3;
        const fv4 xA = (ph == 0) ? pA0 : (ph == 1) ? pA1 : pA2;
        const fv4 xB = (ph == 0) ? pB0 : (ph == 1) ? pB1 : pB2;
        if (a < NA - 3) {
            const fv4 nA = *(const fv4*)(xb + (a + 3) * DM + lane * 4);
            const fv4 nB = *(const fv4*)(xb + (a + 3) * DM + 256 + lane * 4);
            if (ph == 0)      { pA0 = nA; pB0 = nB; }
            else if (ph == 1) { pA1 = nA; pB1 = nB; }
            else              { pA2 = nA; pB2 = nB; }
        }
        float acc[NOH];
#pragma unroll
        for (int oh = 0; oh < NOH; ++oh) {
            float v = xA.x * mA[oh].x;
            v = fmaf(xA.y, mA[oh].y, v);
            v = fmaf(xA.z, mA[oh].z, v);
            v = fmaf(xA.w, mA[oh].w, v);
            v = fmaf(xB.x, mB[oh].x, v);
            v = fmaf(xB.y, mB[oh].y, v);
            v = fmaf(xB.z, mB[oh].z, v);
            v = fmaf(xB.w, mB[oh].w, v);
            acc[oh] = v;
        }
        // transpose-reduce: 3 merge steps leave lane l holding oh=(l&7)'s
        // 8-lane partial; 3 butterflies finish the 64 lanes.
        float r1[4];
#pragma unroll
        for (int q = 0; q < 4; ++q) {
            float keep = m1 ? acc[2 * q + 1] : acc[2 * q];
            float send = m1 ? acc[2 * q]     : acc[2 * q + 1];
            r1[q] = keep + __shfl_xor(send, 1, 64);
        }
        float r2[2];
#pragma unroll
        for (int q = 0; q < 2; ++q) {
            float keep = m2 ? r1[2 * q + 1] : r1[2 * q];
            float send = m2 ? r1[2 * q]     : r1[2 * q + 1];
            r2[q] = keep + __shfl_xor(send, 2, 64);
        }
        float keep = m4 ? r2[1] : r2[0];
        float send = m4 ? r2[0] : r2[1];
        float t = keep + __shfl_xor(send, 4, 64);
        t += __shfl_xor(t, 8, 64);
        t += __shfl_xor(t, 16, 64);
        t += __shfl_xor(t, 32, 64);
        if (lane < NOH) GW[wave][a][lane] = t + s_lane;
    }

    // Same-wave LDS read-back (lgkmcnt-ordered, no barrier needed):
    // this wave writes its own batch's 169 fv4 outputs, coalesced.
    fv4* outb = (fv4*)(out + (size_t)b * (NA * NA * 4));
#pragma unroll
    for (int r = 0; r < 3; ++r) {
        const int t = lane + 64 * r;
        if (t < NA * NA) {
            int i = t / NA, j = t % NA;
            int lo = i < j ? i : j;
            int hi = i < j ? j : i;
            fv4 v;
            v.x = GW[wave][lo][0] + GW[wave][hi][4];
            v.y = GW[wave][lo][1] + GW[wave][hi][5];
            v.z = GW[wave][lo][2] + GW[wave][hi][6];
            v.w = GW[wave][lo][3] + GW[wave][hi][7];
            outb[t] = v;
        }
    }
}

extern "C" void kernel_launch(void* const* d_in, const int* in_sizes, int n_in,
                              void* d_out, int out_size, void* d_ws, size_t ws_size,
                              hipStream_t stream) {
    const float* x  = (const float*)d_in[0];
    const float* W1 = (const float*)d_in[1];
    const float* b1 = (const float*)d_in[2];
    const float* Wc = (const float*)d_in[3];
    const float* bc = (const float*)d_in[4];
    float* out = (float*)d_out;
    const int B = in_sizes[0] / (NA * DM);   // 8192

    float* M = (float*)d_ws;            // 8*512 floats = 16 KB
    float* s = M + NOH * DM;            // 8 floats

    precompute_M<<<8, 512, 0, stream>>>(W1, b1, Wc, bc, M, s);
    edge_main<<<B / WPB, 512, 0, stream>>>(x, M, s, out);
}

// Round 10
// 45.341 us; speedup vs baseline: 1.0206x; 1.0206x over previous
//
#include <hip/hip_runtime.h>
#include <hip/hip_bf16.h>

// out[b,i,j,o] = (x[b,min]·M_lo[o] + s_lo[o]) + (x[b,max]·M_hi[o] + s_hi[o])
// where M_lo[o] = W1^T Wc[o,:100], M_hi[o] = W1^T Wc[o,100:],
//       s_lo[o] = b1·Wc[o,:100] + bc[o], s_hi[o] = b1·Wc[o,100:].
//
// Final (R8 structure, best measured: 45.5 us):
//  - precompute_M: LDS-staged W1, 8 blocks x 512 thr, ~1.5 us
//  - edge_main: fused, barrier-free; one WAVE per batch (4/block);
//    2-deep register prefetch; per-wave LDS slab; no __syncthreads
//    (same-wave LDS write->read ordered by lgkmcnt).

#define NA 13
#define DM 512
#define NOH 8   // 4 outputs x {lo,hi}
#define LEN 100

typedef float fv4 __attribute__((ext_vector_type(4)));

__global__ __launch_bounds__(512) void precompute_M(
    const float* __restrict__ W1, const float* __restrict__ b1,
    const float* __restrict__ Wc, const float* __restrict__ bc,
    float* __restrict__ M, float* __restrict__ s) {
    __shared__ float W1s[LEN * 64];
    const int tid = threadIdx.x;
    const int d_base = blockIdx.x * 64;

#pragma unroll
    for (int r = 0; r < 4; ++r) {
        int idx = tid + r * 512;
        if (idx < LEN * 16) {
            int c = idx >> 4, d4 = idx & 15;
            *(fv4*)(W1s + c * 64 + d4 * 4) =
                *(const fv4*)(W1 + c * DM + d_base + d4 * 4);
        }
    }
    __syncthreads();

    const int oh = tid >> 6;      // wave-uniform: 0..7
    const int d = tid & 63;
    const int o = oh & 3, half = oh >> 2;
    const float* wc = Wc + o * 200 + half * 100;   // wave-uniform pointer

    float a0 = 0.f, a1 = 0.f, a2 = 0.f, a3 = 0.f;
#pragma unroll
    for (int c = 0; c < LEN; c += 4) {
        a0 = fmaf(wc[c + 0], W1s[(c + 0) * 64 + d], a0);
        a1 = fmaf(wc[c + 1], W1s[(c + 1) * 64 + d], a1);
        a2 = fmaf(wc[c + 2], W1s[(c + 2) * 64 + d], a2);
        a3 = fmaf(wc[c + 3], W1s[(c + 3) * 64 + d], a3);
    }
    M[oh * DM + d_base + d] = (a0 + a1) + (a2 + a3);

    if (blockIdx.x == 0) {
        float p = wc[d] * b1[d];
        if (d < LEN - 64) p = fmaf(wc[d + 64], b1[d + 64], p);
#pragma unroll
        for (int m = 32; m >= 1; m >>= 1) p += __shfl_xor(p, m, 64);
        if (d == 0) s[oh] = p + ((half == 0) ? bc[o] : 0.f);
    }
}

__global__ __launch_bounds__(256) void edge_main(
    const float* __restrict__ x, const float* __restrict__ M,
    const float* __restrict__ s, float* __restrict__ out) {
    const int lane = threadIdx.x & 63;
    const int wave = threadIdx.x >> 6;
    const int b = blockIdx.x * 4 + wave;          // one batch per wave

    const float* xb = x + (size_t)b * (NA * DM);

    // 2-deep register prefetch over the 13 rows; first loads issued
    // before the M loads so HBM latency hides under them.
    fv4 pA0, pB0, pA1, pB1;
    pA0 = *(const fv4*)(xb + lane * 4);
    pB0 = *(const fv4*)(xb + 256 + lane * 4);
    pA1 = *(const fv4*)(xb + DM + lane * 4);
    pB1 = *(const fv4*)(xb + DM + 256 + lane * 4);

    // Per-lane M slices: lane covers d = lane*4..+3 and d = 256+lane*4..+3
    fv4 mA[NOH], mB[NOH];
#pragma unroll
    for (int oh = 0; oh < NOH; ++oh) {
        mA[oh] = *(const fv4*)(M + oh * DM + lane * 4);
        mB[oh] = *(const fv4*)(M + oh * DM + 256 + lane * 4);
    }
    const float s_lane = s[lane & 7];

    const bool m1 = (lane & 1) != 0;
    const bool m2 = (lane & 2) != 0;
    const bool m4 = (lane & 4) != 0;

    __shared__ float GW[4][NA][NOH];   // private slab per wave

#pragma unroll
    for (int a = 0; a < NA; ++a) {
        const fv4 xA = (a & 1) ? pA1 : pA0;
        const fv4 xB = (a & 1) ? pB1 : pB0;
        if (a < NA - 2) {
            if (a & 1) {
                pA1 = *(const fv4*)(xb + (a + 2) * DM + lane * 4);
                pB1 = *(const fv4*)(xb + (a + 2) * DM + 256 + lane * 4);
            } else {
                pA0 = *(const fv4*)(xb + (a + 2) * DM + lane * 4);
                pB0 = *(const fv4*)(xb + (a + 2) * DM + 256 + lane * 4);
            }
        }
        float acc[NOH];
#pragma unroll
        for (int oh = 0; oh < NOH; ++oh) {
            float v = xA.x * mA[oh].x;
            v = fmaf(xA.y, mA[oh].y, v);
            v = fmaf(xA.z, mA[oh].z, v);
            v = fmaf(xA.w, mA[oh].w, v);
            v = fmaf(xB.x, mB[oh].x, v);
            v = fmaf(xB.y, mB[oh].y, v);
            v = fmaf(xB.z, mB[oh].z, v);
            v = fmaf(xB.w, mB[oh].w, v);
            acc[oh] = v;
        }
        // transpose-reduce: 3 merge steps leave lane l holding oh=(l&7)'s
        // 8-lane partial; 3 butterflies finish the 64 lanes.
        float r1[4];
#pragma unroll
        for (int q = 0; q < 4; ++q) {
            float keep = m1 ? acc[2 * q + 1] : acc[2 * q];
            float send = m1 ? acc[2 * q]     : acc[2 * q + 1];
            r1[q] = keep + __shfl_xor(send, 1, 64);
        }
        float r2[2];
#pragma unroll
        for (int q = 0; q < 2; ++q) {
            float keep = m2 ? r1[2 * q + 1] : r1[2 * q];
            float send = m2 ? r1[2 * q]     : r1[2 * q + 1];
            r2[q] = keep + __shfl_xor(send, 2, 64);
        }
        float keep = m4 ? r2[1] : r2[0];
        float send = m4 ? r2[0] : r2[1];
        float t = keep + __shfl_xor(send, 4, 64);
        t += __shfl_xor(t, 8, 64);
        t += __shfl_xor(t, 16, 64);
        t += __shfl_xor(t, 32, 64);
        if (lane < NOH) GW[wave][a][lane] = t + s_lane;
    }

    // Same-wave LDS read-back (lgkmcnt-ordered, no barrier needed):
    // this wave writes its own batch's 169 fv4 outputs, coalesced.
    fv4* outb = (fv4*)(out + (size_t)b * (NA * NA * 4));
#pragma unroll
    for (int r = 0; r < 3; ++r) {
        const int t = lane + 64 * r;
        if (t < NA * NA) {
            int i = t / NA, j = t % NA;
            int lo = i < j ? i : j;
            int hi = i < j ? j : i;
            fv4 v;
            v.x = GW[wave][lo][0] + GW[wave][hi][4];
            v.y = GW[wave][lo][1] + GW[wave][hi][5];
            v.z = GW[wave][lo][2] + GW[wave][hi][6];
            v.w = GW[wave][lo][3] + GW[wave][hi][7];
            outb[t] = v;
        }
    }
}

extern "C" void kernel_launch(void* const* d_in, const int* in_sizes, int n_in,
                              void* d_out, int out_size, void* d_ws, size_t ws_size,
                              hipStream_t stream) {
    const float* x  = (const float*)d_in[0];
    const float* W1 = (const float*)d_in[1];
    const float* b1 = (const float*)d_in[2];
    const float* Wc = (const float*)d_in[3];
    const float* bc = (const float*)d_in[4];
    float* out = (float*)d_out;
    const int B = in_sizes[0] / (NA * DM);   // 8192

    float* M = (float*)d_ws;            // 8*512 floats = 16 KB
    float* s = M + NOH * DM;            // 8 floats

    precompute_M<<<8, 512, 0, stream>>>(W1, b1, Wc, bc, M, s);
    edge_main<<<B / 4, 256, 0, stream>>>(x, M, s, out);
}